// Round 2
// baseline (215.395 us; speedup 1.0000x reference)
//
#include <hip/hip_runtime.h>

// ColorHistogramLoss: B=32, C=3, H=W=512, BINS=64.
// loss = mean | hist(input)/N - hist(target)/N | over 96*64 bins.
//
// R2: column-per-lane LDS sub-histograms lh[bin][64] (16 KiB).
//   lane l only touches column l -> bank (bin*64+l)%32 = l%32: 2-way (free),
//   zero within-wave same-address atomic collisions. R1's single shared
//   64-bin histogram was DS-atomic-serialized (4M conflict cycles, 16% HBM).

#define BINS 64
#define PLANES 96          // B*C
#define PLANE_F4 65536     // 512*512/4
#define SEGS 32            // segments per plane
#define SEG_F4 2048        // PLANE_F4/SEGS
#define TPB 256
#define F4T 8              // SEG_F4/TPB float4 per thread per tensor

__device__ __forceinline__ void bump(int* lh, int col, float v, int inc) {
    // searchsorted(linspace(-1,1,64), v, 'right')-1 == floor((v+1)*31.5),
    // v < -1 invalid (skip), clamp top to 63.
    int bin = (int)floorf((v + 1.0f) * 31.5f);
    if (bin >= 0) {
        bin = bin > 63 ? 63 : bin;
        atomicAdd(&lh[(bin << 6) + col], inc);   // lh[bin][col]
    }
}

__global__ __launch_bounds__(TPB) void hist_diff_kernel(
        const float4* __restrict__ in4, const float4* __restrict__ tg4,
        int* __restrict__ gdiff) {
    __shared__ int lh[BINS * 64];                // [bin][column], 16 KiB
    const int tid = threadIdx.x;
    const int col = tid & 63;

    // zero 4096 ints with 256 threads, int4 stores
    {
        int4* p = (int4*)lh;
        const int4 z = {0, 0, 0, 0};
#pragma unroll
        for (int k = 0; k < (BINS * 64 / 4) / TPB; ++k) p[tid + k * TPB] = z;
    }
    __syncthreads();

    const int plane = blockIdx.x >> 5;           // /SEGS
    const int seg   = blockIdx.x & (SEGS - 1);
    const long base = (long)plane * PLANE_F4 + (long)seg * SEG_F4 + tid;

    float4 a[F4T];
#pragma unroll
    for (int k = 0; k < F4T; ++k) a[k] = in4[base + k * TPB];
#pragma unroll
    for (int k = 0; k < F4T; ++k) {
        bump(lh, col, a[k].x, 1); bump(lh, col, a[k].y, 1);
        bump(lh, col, a[k].z, 1); bump(lh, col, a[k].w, 1);
    }
#pragma unroll
    for (int k = 0; k < F4T; ++k) a[k] = tg4[base + k * TPB];
#pragma unroll
    for (int k = 0; k < F4T; ++k) {
        bump(lh, col, a[k].x, -1); bump(lh, col, a[k].y, -1);
        bump(lh, col, a[k].z, -1); bump(lh, col, a[k].w, -1);
    }

    __syncthreads();
    // merge: thread t (t<64) owns bin t; diagonal read lh[t][(t+j)&63]
    // -> bank (t+j)%32 across lanes: all 32 banks, 2-way, conflict-free.
    if (tid < BINS) {
        int s = 0;
#pragma unroll
        for (int j = 0; j < 64; ++j) s += lh[(tid << 6) + ((tid + j) & 63)];
        if (s != 0) atomicAdd(&gdiff[plane * BINS + tid], s);
    }
}

__global__ __launch_bounds__(TPB) void reduce_abs_kernel(
        const int* __restrict__ gdiff, float* __restrict__ out) {
    int s = 0;
    for (int i = threadIdx.x; i < PLANES * BINS; i += TPB) {
        int v = gdiff[i];
        s += (v < 0) ? -v : v;
    }
#pragma unroll
    for (int off = 32; off > 0; off >>= 1) s += __shfl_down(s, off, 64);
    __shared__ int ws[TPB / 64];
    const int wid  = threadIdx.x >> 6;
    const int lane = threadIdx.x & 63;
    if (lane == 0) ws[wid] = s;
    __syncthreads();
    if (threadIdx.x == 0) {
        int total = 0;
#pragma unroll
        for (int w = 0; w < TPB / 64; ++w) total += ws[w];
        out[0] = (float)total * (1.0f / (262144.0f * 6144.0f));
    }
}

extern "C" void kernel_launch(void* const* d_in, const int* in_sizes, int n_in,
                              void* d_out, int out_size, void* d_ws, size_t ws_size,
                              hipStream_t stream) {
    const float4* inp = (const float4*)d_in[0];
    const float4* tgt = (const float4*)d_in[1];
    int* gdiff = (int*)d_ws;   // 96*64 signed counts, 24 KiB

    hipMemsetAsync(gdiff, 0, PLANES * BINS * sizeof(int), stream);
    hist_diff_kernel<<<PLANES * SEGS, TPB, 0, stream>>>(inp, tgt, gdiff);
    reduce_abs_kernel<<<1, TPB, 0, stream>>>(gdiff, (float*)d_out);
}